// Round 22
// baseline (329.041 us; speedup 1.0000x reference)
//
#include <hip/hip_runtime.h>
#include <hip/hip_bf16.h>
#include <stdint.h>

#define B_   64
#define T_   2048
#define ENC_ 1024
#define DEC_ 1024
#define A_   512
#define M_   (B_ * T_)   // 131072

#define BK   64
#define CH   64          // fused-kernel row chunk
#define NCH  (M_ / CH)   // 2048 chunks
#define CPB  (T_ / CH)   // 32 chunks per batch
#define NT   (ENC_ / BK) // 16 K-tiles

typedef __bf16 bf16x8 __attribute__((ext_vector_type(8)));
typedef float  f32x4  __attribute__((ext_vector_type(4)));
typedef unsigned short u16;
typedef u16 u16x8 __attribute__((ext_vector_type(8)));

__device__ __forceinline__ float fast_tanh(float x) {
    float ax = fabsf(x);
    float e  = __expf(-2.0f * ax);     // in (0,1]
    float t  = (1.0f - e) / (1.0f + e);
    return copysignf(t, x);
}

// ---- B pack: Bp[((ks2*4+g)*512 + n)*8 + j] = bf16(U[ks2*32+g*8+j][n]) ----
__global__ __launch_bounds__(256) void k_pack_B(
        const float* __restrict__ U, u16* __restrict__ Bp) {
    int c = blockIdx.x * 256 + threadIdx.x;       // 65536 chunks
    int n   = c & 511;
    int gg  = (c >> 9) & 3;
    int ks2 = c >> 11;
    int kbase = ks2 * 32 + gg * 8;
    u16x8 w;
#pragma unroll
    for (int j = 0; j < 8; ++j) {
        __bf16 v = (__bf16)U[(size_t)(kbase + j) * A_ + n];
        w[j] = *(u16*)&v;
    }
    *(u16x8*)(Bp + (size_t)c * 8) = w;
}

// ---------------- f2[b][a] = sum_e s[b][e] * W[e][a]  (fp32) ---------------
__global__ __launch_bounds__(256) void k_f2(
        const float* __restrict__ s, const float* __restrict__ W,
        float* __restrict__ f2) {
    int b = blockIdx.x;
    int a0 = threadIdx.x;
    const float* srow = s + (size_t)b * DEC_;
    float acc0 = 0.f, acc1 = 0.f;
    for (int e = 0; e < DEC_; ++e) {
        float sv = srow[e];
        acc0 = fmaf(sv, W[(size_t)e * A_ + a0],       acc0);
        acc1 = fmaf(sv, W[(size_t)e * A_ + a0 + 256], acc1);
    }
    f2[(size_t)b * A_ + a0]       = acc0;
    f2[(size_t)b * A_ + a0 + 256] = acc1;
}

// ========== FUSED: GEMM + tanh·V -> e ; online-softmax ctx partials =======
// R21 load placement (loadA at bottom, max slack) + RAW barrier in the loop
// (lgkmcnt(0) + s_barrier -- NO vmcnt drain). R21's regression was
// __syncthreads draining the just-issued HBM loadA at every barrier; the
// raw barrier lets A(t+2)+B(t+1) fly across. Only LDS hazard is the Alds
// dbuf write->read ordering = lgkm. vmcnt never drains to 0 in the loop.
__global__ __launch_bounds__(512, 4) void k_gemm_fused(
        const float* __restrict__ h, const u16* __restrict__ Bp,
        const float* __restrict__ f2, const float* __restrict__ V,
        float* __restrict__ e_full, float* __restrict__ mpart,
        float* __restrict__ spart, float* __restrict__ opart) {
    __shared__ u16 Alds[2][CH * BK];   // 2 x 8 KB, swizzled
    float* ered = (float*)&Alds[0][0]; // [8][64] alias (epilogue only)
    float* wlds = ered + 512;          // [64]    alias (epilogue only)

    const int tid  = threadIdx.x;
    const int lane = tid & 63;
    const int wid  = tid >> 6;         // 0..7 = wave col-slice
    const int lr   = lane & 15;
    const int g    = lane >> 4;
    const int sw   = (lr & 7) << 3;    // A read-side XOR (u16 units)

    // XCD remap: each XCD gets 256 contiguous chunks (= 8 whole batches).
    const int d      = blockIdx.x;     // 0..2047
    const int gchunk = (d & 7) * 256 + (d >> 3);
    const int brow   = gchunk * CH;
    const int b      = gchunk >> 5;    // gchunk / CPB
    const int chunk  = gchunk & 31;

    f32x4 acc[4][4] = {};              // 64 f32 -> AGPRs
    f32x4 ar[2];                       // in-flight A (fp32), 8 regs

    const int arow = tid >> 3;
    const int acol = (tid & 7) * 8;
    auto loadA = [&](int kt) {
        const float* srcA = h + (size_t)(brow + arow) * ENC_ + kt * BK + acol;
        ar[0] = *(const f32x4*)srcA;
        ar[1] = *(const f32x4*)(srcA + 4);
    };
    auto writeA = [&](int buf) {
        u16x8 w;
#pragma unroll
        for (int j = 0; j < 4; ++j) {
            __bf16 lo = (__bf16)ar[0][j], hi = (__bf16)ar[1][j];
            w[j]     = *(u16*)&lo;
            w[j + 4] = *(u16*)&hi;
        }
        *(u16x8*)&Alds[buf][(tid * 8) ^ ((arow & 7) << 3)] = w;
    };
    // B fragments straight from Bp: base for (kt,kk): ((kt*2+kk)*4+g)*512.
    const u16* const bbase = Bp + ((size_t)g * 512 + wid * 64 + lr) * 8;
    auto loadB = [&](int kt, bf16x8 (&b0)[4], bf16x8 (&b1)[4]) {
        const u16* p0 = bbase + (size_t)(kt * 2)     * 4 * 512 * 8;
        const u16* p1 = bbase + (size_t)(kt * 2 + 1) * 4 * 512 * 8;
#pragma unroll
        for (int nf = 0; nf < 4; ++nf) {
            b0[nf] = *(const bf16x8*)(p0 + nf * 16 * 8);
            b1[nf] = *(const bf16x8*)(p1 + nf * 16 * 8);
        }
    };
    auto computeK = [&](int cur, int kk, bf16x8 (&bfr)[4]) {
        bf16x8 af[4];
#pragma unroll
        for (int mf = 0; mf < 4; ++mf)
            af[mf] = *(const bf16x8*)&Alds[cur][
                (((mf * 16 + lr) * 64) + kk * 32 + g * 8) ^ sw];
#pragma unroll
        for (int mf = 0; mf < 4; ++mf)
#pragma unroll
            for (int nf = 0; nf < 4; ++nf)
                acc[mf][nf] = __builtin_amdgcn_mfma_f32_16x16x32_bf16(
                    af[mf], bfr[nf], acc[mf][nf], 0, 0, 0);
    };

#define RBAR()  __builtin_amdgcn_s_barrier()
#define LGKM0() asm volatile("s_waitcnt lgkmcnt(0)" ::: "memory")

    // ---- prologue: A(0) staged; A(1)+B(0) in flight across the barrier ----
    bf16x8 b0[4], b1[4];
    loadA(0);
    writeA(0);                 // implicit wait on A(0) regs
    loadA(1);                  // A(1) flies; consumed at bottom of tile 0
    loadB(0, b0, b1);          // lands under the barrier + tile-0 front
    LGKM0();                   // A(0) ds_writes visible
    RBAR();                    // raw barrier: vmcnt NOT drained

    for (int kt = 0; kt < NT; ++kt) {
        const int cur = kt & 1;
        computeK(cur, 0, b0);             // b-wait: counted, mostly landed
        computeK(cur, 1, b1);
        if (kt + 1 < NT) {
            loadB(kt + 1, b0, b1);        // regs dead after compute; reload
            writeA(cur ^ 1);   // waits ar=A(kt+1): issued 1 tile + bar ago
            if (kt + 2 < NT) loadA(kt + 2);   // flies across raw barrier
            LGKM0();           // ds_writes visible to all waves
            RBAR();            // no vmcnt drain: A+B stay in flight
        }
    }

    // ---- epilogue A: per-wave partial e over its 64-col slice ----
    float vv[4], ff[4];
#pragma unroll
    for (int nf = 0; nf < 4; ++nf) {
        int n = wid * 64 + nf * 16 + lr;
        vv[nf] = V[n];
        ff[nf] = f2[(size_t)b * A_ + n];
    }
    __syncthreads();           // full drain; all compute done before alias
#pragma unroll
    for (int mf = 0; mf < 4; ++mf) {
        float sums[4];
#pragma unroll
        for (int i = 0; i < 4; ++i) {
            float sv = 0.f;
#pragma unroll
            for (int nf = 0; nf < 4; ++nf) {
                float x = acc[mf][nf][i] + ff[nf];
                sv = fmaf(fast_tanh(x), vv[nf], sv);
            }
#pragma unroll
            for (int mm = 1; mm < 16; mm <<= 1)
                sv += __shfl_xor(sv, mm, 64);     // reduce 16 cols
            sums[i] = sv;
        }
        if (lr == 0) {
#pragma unroll
            for (int i = 0; i < 4; ++i)
                ered[wid * 64 + mf * 16 + g * 4 + i] = sums[i];
        }
    }
    __syncthreads();

    // ---- epilogue B: wave 0 reduces 8 slices -> e row, m_b, s_b, w_r ----
    if (tid < 64) {
        float er = 0.f;
#pragma unroll
        for (int w = 0; w < 8; ++w) er += ered[w * 64 + tid];
        float mb = er;
#pragma unroll
        for (int mm = 1; mm < 64; mm <<= 1)
            mb = fmaxf(mb, __shfl_xor(mb, mm, 64));
        float wr_ = __expf(er - mb);
        float sb = wr_;
#pragma unroll
        for (int mm = 1; mm < 64; mm <<= 1)
            sb += __shfl_xor(sb, mm, 64);
        wlds[tid] = wr_;
        e_full[(size_t)b * T_ + chunk * CH + tid] = er;   // RAW e
        if (tid == 0) { mpart[gchunk] = mb; spart[gchunk] = sb; }
    }
    __syncthreads();

    // ---- epilogue C: o[col] = sum_r w_r * h[r][col]  (h is L2/L3-warm) ----
    const int c2 = tid * 2;
    float o0 = 0.f, o1 = 0.f;
#pragma unroll 8
    for (int r = 0; r < CH; ++r) {
        float w = wlds[r];                      // broadcast (free)
        float2 hv = *(const float2*)(h + (size_t)(brow + r) * ENC_ + c2);
        o0 = fmaf(w, hv.x, o0);
        o1 = fmaf(w, hv.y, o1);
    }
    float* op = opart + (size_t)gchunk * ENC_ + c2;
    op[0] = o0; op[1] = o1;
#undef RBAR
#undef LGKM0
}

// ---------------- per-batch flash-merge of 32 chunk partials --------------
__global__ __launch_bounds__(256) void k_ctx_reduce(
        const float* __restrict__ mpart, const float* __restrict__ spart,
        const float* __restrict__ opart, float* __restrict__ c_out,
        float* __restrict__ mg_g, float* __restrict__ sg_g) {
    const int b = blockIdx.x, tid = threadIdx.x;
    __shared__ float esc[CPB];
    __shared__ float mgS, sgS;

    if (tid < CPB) {                       // lanes 0..31 of wave 0
        float mr = mpart[b * CPB + tid];
        float sr = spart[b * CPB + tid];
        float mg = mr;
#pragma unroll
        for (int mm = 1; mm < 32; mm <<= 1)
            mg = fmaxf(mg, __shfl_xor(mg, mm, 32));
        float e = __expf(mr - mg);
        esc[tid] = e;
        float S = sr * e;
#pragma unroll
        for (int mm = 1; mm < 32; mm <<= 1)
            S += __shfl_xor(S, mm, 32);
        if (tid == 0) { mgS = mg; sgS = S; mg_g[b] = mg; sg_g[b] = S; }
    }
    __syncthreads();
    float inv = 1.0f / sgS;
    int c = tid * 4;                       // 1024 cols / 256 threads
    f32x4 av = {0.f, 0.f, 0.f, 0.f};
    for (int r = 0; r < CPB; ++r) {
        f32x4 ov = *(const f32x4*)&opart[((size_t)(b * CPB + r)) * ENC_ + c];
        float e = esc[r];
        av[0] = fmaf(e, ov[0], av[0]); av[1] = fmaf(e, ov[1], av[1]);
        av[2] = fmaf(e, ov[2], av[2]); av[3] = fmaf(e, ov[3], av[3]);
    }
    av[0] *= inv; av[1] *= inv; av[2] *= inv; av[3] *= inv;
    *(f32x4*)&c_out[(size_t)b * ENC_ + c] = av;
}

// ---------------- a = exp(e - m_g) / S_g ----------------------------------
__global__ __launch_bounds__(256) void k_a_final(
        const float* __restrict__ e_full, const float* __restrict__ mg_g,
        const float* __restrict__ sg_g, float* __restrict__ a_out) {
    int idx = blockIdx.x * 256 + threadIdx.x;   // over M_
    int b = idx >> 11;                          // T_ = 2048
    a_out[idx] = __expf(e_full[idx] - mg_g[b]) / sg_g[b];
}

extern "C" void kernel_launch(void* const* d_in, const int* in_sizes, int n_in,
                              void* d_out, int out_size, void* d_ws, size_t ws_size,
                              hipStream_t stream) {
    const float* h = (const float*)d_in[0];
    const float* s = (const float*)d_in[1];
    const float* U = (const float*)d_in[2];
    const float* W = (const float*)d_in[3];
    const float* V = (const float*)d_in[4];

    float* out   = (float*)d_out;
    float* c_out = out;                         // [64][1][1024]
    float* a_out = out + 64 * 1024;             // [64][2048][1]

    char* ws = (char*)d_ws;
    u16*   Bp = (u16*)ws;                                  // 1 MB
    float* f2 = (float*)(ws + (1 << 20));                  // 128 KB
    float* e_full = (float*)(ws + 0x120000);               // 512 KB
    float* mpart  = (float*)(ws + 0x1A0000);               // 8 KB
    float* spart  = (float*)(ws + 0x1A2000);               // 8 KB
    float* mg_g   = (float*)(ws + 0x1A4000);               // 256 B
    float* sg_g   = (float*)(ws + 0x1A4100);               // 256 B
    float* opart  = (float*)(ws + 0x200000);               // 8 MB

    k_pack_B<<<256, 256, 0, stream>>>(U, Bp);
    k_f2<<<64, 256, 0, stream>>>(s, W, f2);

    k_gemm_fused<<<NCH, 512, 0, stream>>>(h, Bp, f2, V,
                                          e_full, mpart, spart, opart);
    k_ctx_reduce<<<64, 256, 0, stream>>>(mpart, spart, opart,
                                         c_out, mg_g, sg_g);
    k_a_final<<<M_ / 256, 256, 0, stream>>>(e_full, mg_g, sg_g, a_out);
}

// Round 23
// 296.013 us; speedup vs baseline: 1.1116x; 1.1116x over previous
//
#include <hip/hip_runtime.h>
#include <hip/hip_bf16.h>
#include <stdint.h>

#define B_   64
#define T_   2048
#define ENC_ 1024
#define DEC_ 1024
#define A_   512
#define M_   (B_ * T_)   // 131072

#define BK   64
#define CH   64          // fused-kernel row chunk
#define NCH  (M_ / CH)   // 2048 chunks
#define CPB  (T_ / CH)   // 32 chunks per batch
#define NT   (ENC_ / BK) // 16 K-tiles

typedef __bf16 bf16x8 __attribute__((ext_vector_type(8)));
typedef float  f32x4  __attribute__((ext_vector_type(4)));
typedef unsigned short u16;
typedef u16 u16x8 __attribute__((ext_vector_type(8)));

__device__ __forceinline__ float fast_tanh(float x) {
    float ax = fabsf(x);
    float e  = __expf(-2.0f * ax);     // in (0,1]
    float t  = (1.0f - e) / (1.0f + e);
    return copysignf(t, x);
}

// ---- B pack: Bp[((ks2*4+g)*512 + n)*8 + j] = bf16(U[ks2*32+g*8+j][n]) ----
__global__ __launch_bounds__(256) void k_pack_B(
        const float* __restrict__ U, u16* __restrict__ Bp) {
    int c = blockIdx.x * 256 + threadIdx.x;       // 65536 chunks
    int n   = c & 511;
    int gg  = (c >> 9) & 3;
    int ks2 = c >> 11;
    int kbase = ks2 * 32 + gg * 8;
    u16x8 w;
#pragma unroll
    for (int j = 0; j < 8; ++j) {
        __bf16 v = (__bf16)U[(size_t)(kbase + j) * A_ + n];
        w[j] = *(u16*)&v;
    }
    *(u16x8*)(Bp + (size_t)c * 8) = w;
}

// ---------------- f2[b][a] = sum_e s[b][e] * W[e][a]  (fp32) ---------------
__global__ __launch_bounds__(256) void k_f2(
        const float* __restrict__ s, const float* __restrict__ W,
        float* __restrict__ f2) {
    int b = blockIdx.x;
    int a0 = threadIdx.x;
    const float* srow = s + (size_t)b * DEC_;
    float acc0 = 0.f, acc1 = 0.f;
    for (int e = 0; e < DEC_; ++e) {
        float sv = srow[e];
        acc0 = fmaf(sv, W[(size_t)e * A_ + a0],       acc0);
        acc1 = fmaf(sv, W[(size_t)e * A_ + a0 + 256], acc1);
    }
    f2[(size_t)b * A_ + a0]       = acc0;
    f2[(size_t)b * A_ + a0 + 256] = acc1;
}

// ========== FUSED: GEMM + tanh·V -> e ; online-softmax ctx partials =======
// R19 final: one block = 64 rows x FULL A=512, 512 threads, 8 waves 1x8,
// wave tile 64x64 (acc = 64 AGPR). A: HBM->regs->bf16->LDS dbuf 2x8KB (T2
// swizzle), loadA(t+1) at tile top (~compute slack). B: fragment-order Bp
// direct from L2 (no LDS round trip); loadB(t+1) rotated to post-compute so
// its latency hides under writeA+barrier. 1 barrier/tile; LDS 16KB ->
// 2 blocks/CU; co-resident block covers residual stalls.
__global__ __launch_bounds__(512, 4) void k_gemm_fused(
        const float* __restrict__ h, const u16* __restrict__ Bp,
        const float* __restrict__ f2, const float* __restrict__ V,
        float* __restrict__ e_full, float* __restrict__ mpart,
        float* __restrict__ spart, float* __restrict__ opart) {
    __shared__ u16 Alds[2][CH * BK];   // 2 x 8 KB, swizzled
    float* ered = (float*)&Alds[0][0]; // [8][64] alias (epilogue only)
    float* wlds = ered + 512;          // [64]    alias (epilogue only)

    const int tid  = threadIdx.x;
    const int lane = tid & 63;
    const int wid  = tid >> 6;         // 0..7 = wave col-slice
    const int lr   = lane & 15;
    const int g    = lane >> 4;
    const int sw   = (lr & 7) << 3;    // A read-side XOR (u16 units)

    // XCD remap: each XCD gets 256 contiguous chunks (= 8 whole batches).
    const int d      = blockIdx.x;     // 0..2047
    const int gchunk = (d & 7) * 256 + (d >> 3);
    const int brow   = gchunk * CH;
    const int b      = gchunk >> 5;    // gchunk / CPB
    const int chunk  = gchunk & 31;

    f32x4 acc[4][4] = {};              // 64 f32 -> AGPRs
    f32x4 ar[2];                       // in-flight A (fp32), 8 regs

    const int arow = tid >> 3;
    const int acol = (tid & 7) * 8;
    auto loadA = [&](int kt) {
        const float* srcA = h + (size_t)(brow + arow) * ENC_ + kt * BK + acol;
        ar[0] = *(const f32x4*)srcA;
        ar[1] = *(const f32x4*)(srcA + 4);
    };
    auto writeA = [&](int buf) {
        u16x8 w;
#pragma unroll
        for (int j = 0; j < 4; ++j) {
            __bf16 lo = (__bf16)ar[0][j], hi = (__bf16)ar[1][j];
            w[j]     = *(u16*)&lo;
            w[j + 4] = *(u16*)&hi;
        }
        *(u16x8*)&Alds[buf][(tid * 8) ^ ((arow & 7) << 3)] = w;
    };
    // B fragments straight from Bp: base for (kt,kk): ((kt*2+kk)*4+g)*512.
    const u16* const bbase = Bp + ((size_t)g * 512 + wid * 64 + lr) * 8;
    auto loadB = [&](int kt, bf16x8 (&b0)[4], bf16x8 (&b1)[4]) {
        const u16* p0 = bbase + (size_t)(kt * 2)     * 4 * 512 * 8;
        const u16* p1 = bbase + (size_t)(kt * 2 + 1) * 4 * 512 * 8;
#pragma unroll
        for (int nf = 0; nf < 4; ++nf) {
            b0[nf] = *(const bf16x8*)(p0 + nf * 16 * 8);
            b1[nf] = *(const bf16x8*)(p1 + nf * 16 * 8);
        }
    };
    auto computeK = [&](int cur, int kk, bf16x8 (&bfr)[4]) {
        bf16x8 af[4];
#pragma unroll
        for (int mf = 0; mf < 4; ++mf)
            af[mf] = *(const bf16x8*)&Alds[cur][
                (((mf * 16 + lr) * 64) + kk * 32 + g * 8) ^ sw];
#pragma unroll
        for (int mf = 0; mf < 4; ++mf)
#pragma unroll
            for (int nf = 0; nf < 4; ++nf)
                acc[mf][nf] = __builtin_amdgcn_mfma_f32_16x16x32_bf16(
                    af[mf], bfr[nf], acc[mf][nf], 0, 0, 0);
    };

    // ---- prologue: A(0) staged; B(0) in flight across the barrier ----
    bf16x8 b0[4], b1[4];
    loadA(0);
    writeA(0);                 // implicit wait on A(0) regs
    loadB(0, b0, b1);          // issued before barrier, lands during it
    __syncthreads();

    for (int kt = 0; kt < NT; ++kt) {
        const int cur = kt & 1;
        if (kt + 1 < NT) loadA(kt + 1);   // HBM loads, ~compute-long slack
        computeK(cur, 0, b0);             // waits b0 (mostly landed)
        computeK(cur, 1, b1);
        if (kt + 1 < NT) {
            loadB(kt + 1, b0, b1);        // regs dead after compute; reload
            writeA(cur ^ 1);   // waits ar only (older); B stays in flight
            __syncthreads();   // B loads keep flying across barrier
        }
    }

    // ---- epilogue A: per-wave partial e over its 64-col slice ----
    float vv[4], ff[4];
#pragma unroll
    for (int nf = 0; nf < 4; ++nf) {
        int n = wid * 64 + nf * 16 + lr;
        vv[nf] = V[n];
        ff[nf] = f2[(size_t)b * A_ + n];
    }
    __syncthreads();           // all compute done before ered aliases Alds
#pragma unroll
    for (int mf = 0; mf < 4; ++mf) {
        float sums[4];
#pragma unroll
        for (int i = 0; i < 4; ++i) {
            float sv = 0.f;
#pragma unroll
            for (int nf = 0; nf < 4; ++nf) {
                float x = acc[mf][nf][i] + ff[nf];
                sv = fmaf(fast_tanh(x), vv[nf], sv);
            }
#pragma unroll
            for (int mm = 1; mm < 16; mm <<= 1)
                sv += __shfl_xor(sv, mm, 64);     // reduce 16 cols
            sums[i] = sv;
        }
        if (lr == 0) {
#pragma unroll
            for (int i = 0; i < 4; ++i)
                ered[wid * 64 + mf * 16 + g * 4 + i] = sums[i];
        }
    }
    __syncthreads();

    // ---- epilogue B: wave 0 reduces 8 slices -> e row, m_b, s_b, w_r ----
    if (tid < 64) {
        float er = 0.f;
#pragma unroll
        for (int w = 0; w < 8; ++w) er += ered[w * 64 + tid];
        float mb = er;
#pragma unroll
        for (int mm = 1; mm < 64; mm <<= 1)
            mb = fmaxf(mb, __shfl_xor(mb, mm, 64));
        float wr_ = __expf(er - mb);
        float sb = wr_;
#pragma unroll
        for (int mm = 1; mm < 64; mm <<= 1)
            sb += __shfl_xor(sb, mm, 64);
        wlds[tid] = wr_;
        e_full[(size_t)b * T_ + chunk * CH + tid] = er;   // RAW e
        if (tid == 0) { mpart[gchunk] = mb; spart[gchunk] = sb; }
    }
    __syncthreads();

    // ---- epilogue C: o[col] = sum_r w_r * h[r][col]  (h is L2/L3-warm) ----
    const int c2 = tid * 2;
    float o0 = 0.f, o1 = 0.f;
#pragma unroll 8
    for (int r = 0; r < CH; ++r) {
        float w = wlds[r];                      // broadcast (free)
        float2 hv = *(const float2*)(h + (size_t)(brow + r) * ENC_ + c2);
        o0 = fmaf(w, hv.x, o0);
        o1 = fmaf(w, hv.y, o1);
    }
    float* op = opart + (size_t)gchunk * ENC_ + c2;
    op[0] = o0; op[1] = o1;
}

// ---------------- per-batch flash-merge of 32 chunk partials --------------
__global__ __launch_bounds__(256) void k_ctx_reduce(
        const float* __restrict__ mpart, const float* __restrict__ spart,
        const float* __restrict__ opart, float* __restrict__ c_out,
        float* __restrict__ mg_g, float* __restrict__ sg_g) {
    const int b = blockIdx.x, tid = threadIdx.x;
    __shared__ float esc[CPB];
    __shared__ float mgS, sgS;

    if (tid < CPB) {                       // lanes 0..31 of wave 0
        float mr = mpart[b * CPB + tid];
        float sr = spart[b * CPB + tid];
        float mg = mr;
#pragma unroll
        for (int mm = 1; mm < 32; mm <<= 1)
            mg = fmaxf(mg, __shfl_xor(mg, mm, 32));
        float e = __expf(mr - mg);
        esc[tid] = e;
        float S = sr * e;
#pragma unroll
        for (int mm = 1; mm < 32; mm <<= 1)
            S += __shfl_xor(S, mm, 32);
        if (tid == 0) { mgS = mg; sgS = S; mg_g[b] = mg; sg_g[b] = S; }
    }
    __syncthreads();
    float inv = 1.0f / sgS;
    int c = tid * 4;                       // 1024 cols / 256 threads
    f32x4 av = {0.f, 0.f, 0.f, 0.f};
    for (int r = 0; r < CPB; ++r) {
        f32x4 ov = *(const f32x4*)&opart[((size_t)(b * CPB + r)) * ENC_ + c];
        float e = esc[r];
        av[0] = fmaf(e, ov[0], av[0]); av[1] = fmaf(e, ov[1], av[1]);
        av[2] = fmaf(e, ov[2], av[2]); av[3] = fmaf(e, ov[3], av[3]);
    }
    av[0] *= inv; av[1] *= inv; av[2] *= inv; av[3] *= inv;
    *(f32x4*)&c_out[(size_t)b * ENC_ + c] = av;
}

// ---------------- a = exp(e - m_g) / S_g ----------------------------------
__global__ __launch_bounds__(256) void k_a_final(
        const float* __restrict__ e_full, const float* __restrict__ mg_g,
        const float* __restrict__ sg_g, float* __restrict__ a_out) {
    int idx = blockIdx.x * 256 + threadIdx.x;   // over M_
    int b = idx >> 11;                          // T_ = 2048
    a_out[idx] = __expf(e_full[idx] - mg_g[b]) / sg_g[b];
}

extern "C" void kernel_launch(void* const* d_in, const int* in_sizes, int n_in,
                              void* d_out, int out_size, void* d_ws, size_t ws_size,
                              hipStream_t stream) {
    const float* h = (const float*)d_in[0];
    const float* s = (const float*)d_in[1];
    const float* U = (const float*)d_in[2];
    const float* W = (const float*)d_in[3];
    const float* V = (const float*)d_in[4];

    float* out   = (float*)d_out;
    float* c_out = out;                         // [64][1][1024]
    float* a_out = out + 64 * 1024;             // [64][2048][1]

    char* ws = (char*)d_ws;
    u16*   Bp = (u16*)ws;                                  // 1 MB
    float* f2 = (float*)(ws + (1 << 20));                  // 128 KB
    float* e_full = (float*)(ws + 0x120000);               // 512 KB
    float* mpart  = (float*)(ws + 0x1A0000);               // 8 KB
    float* spart  = (float*)(ws + 0x1A2000);               // 8 KB
    float* mg_g   = (float*)(ws + 0x1A4000);               // 256 B
    float* sg_g   = (float*)(ws + 0x1A4100);               // 256 B
    float* opart  = (float*)(ws + 0x200000);               // 8 MB

    k_pack_B<<<256, 256, 0, stream>>>(U, Bp);
    k_f2<<<64, 256, 0, stream>>>(s, W, f2);

    k_gemm_fused<<<NCH, 512, 0, stream>>>(h, Bp, f2, V,
                                          e_full, mpart, spart, opart);
    k_ctx_reduce<<<64, 256, 0, stream>>>(mpart, spart, opart,
                                         c_out, mg_g, sg_g);
    k_a_final<<<M_ / 256, 256, 0, stream>>>(e_full, mg_g, sg_g, a_out);
}